// Round 7
// baseline (244.685 us; speedup 1.0000x reference)
//
#include <hip/hip_runtime.h>

static constexpr int FIN = 128;
static constexpr int HD  = 64;
static constexpr int CD  = 40;
static constexpr int S2  = 48;      // padded stride for layer-2 node rows
static constexpr int SLB = 72;      // LDS slab stride (bf16), 64+8 pad

typedef __attribute__((ext_vector_type(8))) short short8;   // 8 bf16 = 4 VGPR
typedef __attribute__((ext_vector_type(4))) float f32x4;    // MFMA acc

__device__ __forceinline__ unsigned short f2b(float f)      // fp32->bf16 RNE
{
    union { float f; unsigned u; } x; x.f = f;
    unsigned u = x.u;
    return (unsigned short)((u + 0x7FFF + ((u >> 16) & 1)) >> 16);
}
__device__ __forceinline__ float b2f(unsigned short b)
{
    union { unsigned u; float f; } x; x.u = ((unsigned)b) << 16;
    return x.f;
}

static constexpr int NBMAX = 512;   // buckets of 256 nodes (n<=131072)
static constexpr int ACH   = 4096;  // edges per phase-A block

// ---------------------------------------------------------------------------
// prep: all 6 weight conversions (fp32 -> padded bf16) + zero bucketCount.
// ---------------------------------------------------------------------------
__global__ __launch_bounds__(256)
void prep_kernel(const float* __restrict__ w1_lin, const float* __restrict__ w1_o1,
                 const float* __restrict__ w1_o2, const float* __restrict__ w2_lin,
                 const float* __restrict__ w2_o1, const float* __restrict__ w2_o2,
                 unsigned short* __restrict__ wb, int* __restrict__ bucketCount)
{
    int i = blockIdx.x * 256 + threadIdx.x;
    if (i < NBMAX) bucketCount[i] = 0;
    if (i >= 25600) return;
    const float* src; int Kin, Kp, Oin, off;
    if (i < 8192)       { src = w1_lin; Kin = 128; Kp = 128; Oin = 64; off = 0; }
    else if (i < 12288) { src = w1_o1;  Kin = 64;  Kp = 64;  Oin = 64; off = 8192; }
    else if (i < 16384) { src = w1_o2;  Kin = 64;  Kp = 64;  Oin = 64; off = 12288; }
    else if (i < 19456) { src = w2_lin; Kin = 64;  Kp = 64;  Oin = 40; off = 16384; }
    else if (i < 22528) { src = w2_o1;  Kin = 40;  Kp = 64;  Oin = 40; off = 19456; }
    else                { src = w2_o2;  Kin = 40;  Kp = 64;  Oin = 40; off = 22528; }
    int j = i - off;
    int o = j / Kp, k = j - o * Kp;
    float v = (o < Oin && k < Kin) ? src[o * Kin + k] : 0.f;
    wb[i] = f2b(v);
}

// ---------------------------------------------------------------------------
// MFMA tile helper (verified index math) — used by mv1.
// ---------------------------------------------------------------------------
template<int NKT, int NOT>
__device__ __forceinline__ void mfma_tile(const short8* a, const unsigned short* __restrict__ Wbf,
                                          int l16, int quad, f32x4* acc)
{
    constexpr int KP = NKT * 32;
#pragma unroll
    for (int ot = 0; ot < NOT; ++ot) {
        acc[ot] = (f32x4){0.f, 0.f, 0.f, 0.f};
        const unsigned short* Wrow = Wbf + (size_t)(ot * 16 + l16) * KP + quad * 8;
#pragma unroll
        for (int kt = 0; kt < NKT; ++kt) {
            short8 b = *reinterpret_cast<const short8*>(Wrow + kt * 32);
            acc[ot] = __builtin_amdgcn_mfma_f32_16x16x32_bf16(a[kt], b, acc[ot], 0, 0, 0);
        }
    }
}

// per-wave single-output-slab matvec on a 16-row LDS slab (K=64)
__device__ __forceinline__ f32x4 mv16(const unsigned short* slab,
                                      const unsigned short* __restrict__ Wbf,
                                      int o, int l16, int quad)
{
    short8 a0 = *reinterpret_cast<const short8*>(&slab[l16 * SLB + quad * 8]);
    short8 a1 = *reinterpret_cast<const short8*>(&slab[l16 * SLB + 32 + quad * 8]);
    const unsigned short* Wrow = Wbf + (size_t)o * 64 + quad * 8;
    short8 b0 = *reinterpret_cast<const short8*>(Wrow);
    short8 b1 = *reinterpret_cast<const short8*>(Wrow + 32);
    f32x4 acc = (f32x4){0.f, 0.f, 0.f, 0.f};
    acc = __builtin_amdgcn_mfma_f32_16x16x32_bf16(a0, b0, acc, 0, 0, 0);
    acc = __builtin_amdgcn_mfma_f32_16x16x32_bf16(a1, b1, acc, 0, 0, 0);
    return acc;
}

// ---------------------------------------------------------------------------
// Fused conv1-lin mv + bhist (R1 verbatim: 256-node buckets, dst>>8).
// ---------------------------------------------------------------------------
__global__ __launch_bounds__(256)
void mv1_bhist_kernel(const float* __restrict__ x, const unsigned short* __restrict__ wb1_lin,
                      const float* __restrict__ b1_lin, unsigned short* __restrict__ h,
                      int n, int tgrid,
                      const int* __restrict__ dst, int* __restrict__ bucketCount, int e, int nb)
{
    __shared__ int cnt[NBMAX];
    if (blockIdx.x >= tgrid) {
        const int bb = blockIdx.x - tgrid;
        const int t = threadIdx.x;
        for (int j = t; j < nb; j += 256) cnt[j] = 0;
        __syncthreads();
        const int i0 = bb * ACH;
        const int i1 = min(e, i0 + ACH);
        for (int i = i0 + t; i < i1; i += 256)
            atomicAdd(&cnt[dst[i] >> 8], 1);
        __syncthreads();
        for (int j = t; j < nb; j += 256)
            if (cnt[j]) atomicAdd(&bucketCount[j], cnt[j]);
        return;
    }
    const int t = threadIdx.x, wave = t >> 6, lane = t & 63;
    const int quad = lane >> 4, l16 = lane & 15;
    const int n0 = blockIdx.x * 64, m0 = wave * 16;
    int row = n0 + m0 + l16; if (row >= n) row = n - 1;

    short8 a[4];
#pragma unroll
    for (int kt = 0; kt < 4; ++kt) {
        const float* p = x + (size_t)row * FIN + kt * 32 + quad * 8;
        float4 f0 = *reinterpret_cast<const float4*>(p);
        float4 f1 = *reinterpret_cast<const float4*>(p + 4);
        short8 v;
        v[0] = (short)f2b(f0.x); v[1] = (short)f2b(f0.y);
        v[2] = (short)f2b(f0.z); v[3] = (short)f2b(f0.w);
        v[4] = (short)f2b(f1.x); v[5] = (short)f2b(f1.y);
        v[6] = (short)f2b(f1.z); v[7] = (short)f2b(f1.w);
        a[kt] = v;
    }
    f32x4 acc[4];
    mfma_tile<4, 4>(a, wb1_lin, l16, quad, acc);
#pragma unroll
    for (int ot = 0; ot < 4; ++ot) {
        int o = ot * 16 + l16;
        float bv = b1_lin[o];
#pragma unroll
        for (int r = 0; r < 4; ++r) {
            int node = n0 + m0 + quad * 4 + r;
            if (node < n) h[(size_t)node * HD + o] = f2b(acc[ot][r] + bv);
        }
    }
}

// ---------------------------------------------------------------------------
// CSR build (R1 verbatim: 256-node buckets).
// ---------------------------------------------------------------------------
__global__ __launch_bounds__(256)
void bscan_kernel(const int* __restrict__ bucketCount, int* __restrict__ bucketOff,
                  int* __restrict__ bucketCursor, int nb)
{
    __shared__ int sA[NBMAX], sB[NBMAX];
    const int t = threadIdx.x;
#pragma unroll
    for (int s = t; s < NBMAX; s += 256) sA[s] = (s < nb) ? bucketCount[s] : 0;
    __syncthreads();
    int* pa = sA; int* pb = sB;
    for (int off = 1; off < NBMAX; off <<= 1) {
#pragma unroll
        for (int s = t; s < NBMAX; s += 256)
            pb[s] = pa[s] + ((s >= off) ? pa[s - off] : 0);
        __syncthreads();
        int* tmp = pa; pa = pb; pb = tmp;
    }
#pragma unroll
    for (int s = t; s <= nb && s < NBMAX; s += 256) {
        int v = (s == 0) ? 0 : pa[s - 1];
        bucketOff[s] = v;
        if (s < nb) bucketCursor[s] = v;
    }
}

__global__ __launch_bounds__(256)
void bpart_kernel(const int* __restrict__ src, const int* __restrict__ dst,
                  int* __restrict__ bucketCursor, uint2* __restrict__ pairs,
                  int e, int nb)
{
    __shared__ int cnt[NBMAX];
    __shared__ int base[NBMAX];
    const int t = threadIdx.x;
    for (int j = t; j < nb; j += 256) cnt[j] = 0;
    __syncthreads();
    const int i0 = blockIdx.x * ACH;
    const int i1 = min(e, i0 + ACH);
    for (int i = i0 + t; i < i1; i += 256)
        atomicAdd(&cnt[dst[i] >> 8], 1);
    __syncthreads();
    for (int j = t; j < nb; j += 256) {
        int c = cnt[j];
        base[j] = c ? atomicAdd(&bucketCursor[j], c) : 0;
        cnt[j] = 0;
    }
    __syncthreads();
    for (int i = i0 + t; i < i1; i += 256) {
        int d = dst[i];
        int bkt = d >> 8;
        int pos = base[bkt] + atomicAdd(&cnt[bkt], 1);
        pairs[pos] = make_uint2((unsigned)d, (unsigned)src[i]);
    }
}

__global__ __launch_bounds__(256)
void bbuild_kernel(const uint2* __restrict__ pairs, const int* __restrict__ bucketOff,
                   int* __restrict__ rowptr_end, int* __restrict__ deg_g,
                   int* __restrict__ eidx, int n)
{
    __shared__ int deg[256], sA[256], sB[256], cur[256];
    const int t = threadIdx.x;
    const int b = blockIdx.x;
    const int node0 = b << 8;
    const int e0 = bucketOff[b], e1 = bucketOff[b + 1];

    deg[t] = 0;
    __syncthreads();
    for (int i = e0 + t; i < e1; i += 256)
        atomicAdd(&deg[pairs[i].x & 255], 1);
    __syncthreads();
    sA[t] = deg[t];
    __syncthreads();
    int* pa = sA; int* pb = sB;
    for (int off = 1; off < 256; off <<= 1) {
        pb[t] = pa[t] + ((t >= off) ? pa[t - off] : 0);
        __syncthreads();
        int* tmp = pa; pa = pb; pb = tmp;
    }
    const int node = node0 + t;
    if (node < n) {
        rowptr_end[node] = e0 + pa[t];
        deg_g[node] = deg[t];
    }
    cur[t] = pa[t] - deg[t];
    __syncthreads();
    for (int i = e0 + t; i < e1; i += 256) {
        uint2 p = pairs[i];
        int pos = e0 + atomicAdd(&cur[p.x & 255], 1);
        eidx[pos] = (int)p.y;
    }
}

// ---------------------------------------------------------------------------
// gather phase (R1 design-A geometry) with 8-deep manual unroll of the edge
// loop: 8 independent ushort4 gathers issued before any accumulate consumes
// them -> up to 32 edges in flight per wave (4 groups x 8). Summation order
// unchanged (adds applied in j order). Result relu'd into slabA.
// ---------------------------------------------------------------------------
template<int STRIDE, int LPN>
__device__ __forceinline__ void gather_relu_slab(
    const int* __restrict__ rowptr_end, const int* __restrict__ deg_g,
    const int* __restrict__ eidx, const unsigned short* __restrict__ h,
    unsigned short* slabA, int node0, int n, int wave, int grp, int l16)
{
    const int r16 = wave * 4 + grp;
    const int node = node0 + r16;
    const int nodec = (node < n) ? node : (n - 1);
    const bool act = (l16 < LPN);
    const int c0 = l16 * 4;
    const int g16 = grp * 16;

    float a0 = 0.f, a1 = 0.f, a2 = 0.f, a3 = 0.f;
    if (act) {
        ushort4 v = *reinterpret_cast<const ushort4*>(h + (size_t)nodec * STRIDE + c0);
        a0 = b2f(v.x); a1 = b2f(v.y); a2 = b2f(v.z); a3 = b2f(v.w);
    }
    int end   = rowptr_end[nodec];
    int start = end - deg_g[nodec];
    if (node >= n) end = start;

    for (int base = start; base < end; base += 16) {
        int m = min(16, end - base);
        int sv = (l16 < m) ? eidx[base + l16] : 0;
        int j = 0;
        for (; j + 8 <= m; j += 8) {
            int s0 = __shfl(sv, g16 + j,     64);
            int s1 = __shfl(sv, g16 + j + 1, 64);
            int s2 = __shfl(sv, g16 + j + 2, 64);
            int s3 = __shfl(sv, g16 + j + 3, 64);
            int s4 = __shfl(sv, g16 + j + 4, 64);
            int s5 = __shfl(sv, g16 + j + 5, 64);
            int s6 = __shfl(sv, g16 + j + 6, 64);
            int s7 = __shfl(sv, g16 + j + 7, 64);
            if (act) {
                ushort4 w0 = *reinterpret_cast<const ushort4*>(h + (size_t)s0 * STRIDE + c0);
                ushort4 w1 = *reinterpret_cast<const ushort4*>(h + (size_t)s1 * STRIDE + c0);
                ushort4 w2 = *reinterpret_cast<const ushort4*>(h + (size_t)s2 * STRIDE + c0);
                ushort4 w3 = *reinterpret_cast<const ushort4*>(h + (size_t)s3 * STRIDE + c0);
                ushort4 w4 = *reinterpret_cast<const ushort4*>(h + (size_t)s4 * STRIDE + c0);
                ushort4 w5 = *reinterpret_cast<const ushort4*>(h + (size_t)s5 * STRIDE + c0);
                ushort4 w6 = *reinterpret_cast<const ushort4*>(h + (size_t)s6 * STRIDE + c0);
                ushort4 w7 = *reinterpret_cast<const ushort4*>(h + (size_t)s7 * STRIDE + c0);
                a0 += b2f(w0.x); a1 += b2f(w0.y); a2 += b2f(w0.z); a3 += b2f(w0.w);
                a0 += b2f(w1.x); a1 += b2f(w1.y); a2 += b2f(w1.z); a3 += b2f(w1.w);
                a0 += b2f(w2.x); a1 += b2f(w2.y); a2 += b2f(w2.z); a3 += b2f(w2.w);
                a0 += b2f(w3.x); a1 += b2f(w3.y); a2 += b2f(w3.z); a3 += b2f(w3.w);
                a0 += b2f(w4.x); a1 += b2f(w4.y); a2 += b2f(w4.z); a3 += b2f(w4.w);
                a0 += b2f(w5.x); a1 += b2f(w5.y); a2 += b2f(w5.z); a3 += b2f(w5.w);
                a0 += b2f(w6.x); a1 += b2f(w6.y); a2 += b2f(w6.z); a3 += b2f(w6.w);
                a0 += b2f(w7.x); a1 += b2f(w7.y); a2 += b2f(w7.z); a3 += b2f(w7.w);
            }
        }
        for (; j + 4 <= m; j += 4) {
            int s0 = __shfl(sv, g16 + j,     64);
            int s1 = __shfl(sv, g16 + j + 1, 64);
            int s2 = __shfl(sv, g16 + j + 2, 64);
            int s3 = __shfl(sv, g16 + j + 3, 64);
            if (act) {
                ushort4 w0 = *reinterpret_cast<const ushort4*>(h + (size_t)s0 * STRIDE + c0);
                ushort4 w1 = *reinterpret_cast<const ushort4*>(h + (size_t)s1 * STRIDE + c0);
                ushort4 w2 = *reinterpret_cast<const ushort4*>(h + (size_t)s2 * STRIDE + c0);
                ushort4 w3 = *reinterpret_cast<const ushort4*>(h + (size_t)s3 * STRIDE + c0);
                a0 += b2f(w0.x); a1 += b2f(w0.y); a2 += b2f(w0.z); a3 += b2f(w0.w);
                a0 += b2f(w1.x); a1 += b2f(w1.y); a2 += b2f(w1.z); a3 += b2f(w1.w);
                a0 += b2f(w2.x); a1 += b2f(w2.y); a2 += b2f(w2.z); a3 += b2f(w2.w);
                a0 += b2f(w3.x); a1 += b2f(w3.y); a2 += b2f(w3.z); a3 += b2f(w3.w);
            }
        }
        for (; j < m; ++j) {
            int s = __shfl(sv, g16 + j, 64);
            if (act) {
                ushort4 v = *reinterpret_cast<const ushort4*>(h + (size_t)s * STRIDE + c0);
                a0 += b2f(v.x); a1 += b2f(v.y); a2 += b2f(v.z); a3 += b2f(v.w);
            }
        }
    }
    if (act) {
        ushort4 o;
        o.x = f2b(fmaxf(a0, 0.f)); o.y = f2b(fmaxf(a1, 0.f));
        o.z = f2b(fmaxf(a2, 0.f)); o.w = f2b(fmaxf(a3, 0.f));
        *reinterpret_cast<ushort4*>(&slabA[r16 * SLB + c0]) = o;
    }
}

// ---------------------------------------------------------------------------
// gchainB: gather1 (h [n][64]) + {W1_o1+relu, W1_o2+relu, W2_lin} -> bf16 [n][48].
// One block = 16 nodes = one MFMA slab; 4 waves co-op, wave w owns out cols w*16.
// Rider blocks [ggrid, ggrid+cgrid): copy CSR (e+2n ints, contiguous in d_out)
// into the dead pairs region of ws so gchainC can read it while writing d_out.
// ---------------------------------------------------------------------------
__global__ __launch_bounds__(256)
void gchainB_kernel(const int* __restrict__ rowptr_end, const int* __restrict__ deg_g,
                    const int* __restrict__ eidx, const unsigned short* __restrict__ h,
                    const unsigned short* __restrict__ wo1, const float* __restrict__ bo1,
                    const unsigned short* __restrict__ wo2, const float* __restrict__ bo2,
                    const unsigned short* __restrict__ wlin, const float* __restrict__ blin,
                    unsigned short* __restrict__ out, int n, int ggrid,
                    const int4* __restrict__ csr_src, int4* __restrict__ csr_dst, int c4)
{
    if (blockIdx.x >= ggrid) {           // CSR shadow-copy rider (read-read on d_out)
        const int stride = (gridDim.x - ggrid) * 256;
        for (int i = (blockIdx.x - ggrid) * 256 + threadIdx.x; i < c4; i += stride)
            csr_dst[i] = csr_src[i];
        return;
    }

    __shared__ unsigned short slabA[16 * SLB];
    __shared__ unsigned short slabB[16 * SLB];
    const int t = threadIdx.x, wave = t >> 6, lane = t & 63;
    const int quad = lane >> 4, l16 = lane & 15;
    const int node0 = blockIdx.x * 16;

    gather_relu_slab<HD, 16>(rowptr_end, deg_g, eidx, h, slabA, node0, n, wave, quad, l16);
    __syncthreads();

    {   // @W1_o1 + b, relu -> slabB
        int o = wave * 16 + l16;
        f32x4 acc = mv16(slabA, wo1, o, l16, quad);
        float bv = bo1[o];
#pragma unroll
        for (int r = 0; r < 4; ++r)
            slabB[(quad * 4 + r) * SLB + o] = f2b(fmaxf(acc[r] + bv, 0.f));
    }
    __syncthreads();
    {   // @W1_o2 + b, top-level relu -> slabA
        int o = wave * 16 + l16;
        f32x4 acc = mv16(slabB, wo2, o, l16, quad);
        float bv = bo2[o];
#pragma unroll
        for (int r = 0; r < 4; ++r)
            slabA[(quad * 4 + r) * SLB + o] = f2b(fmaxf(acc[r] + bv, 0.f));
    }
    __syncthreads();
    if (wave < 3) {   // @W2_lin + b -> global bf16 [n][48], cols 40..47 = 0
        int o = wave * 16 + l16;
        f32x4 acc = mv16(slabA, wlin, o, l16, quad);
        float bv = (o < CD) ? blin[o] : 0.f;
#pragma unroll
        for (int r = 0; r < 4; ++r) {
            int node = node0 + quad * 4 + r;
            if (node < n) {
                float v = (o < CD) ? (acc[r] + bv) : 0.f;
                out[(size_t)node * S2 + o] = f2b(v);
            }
        }
    }
}

// ---------------------------------------------------------------------------
// gchainC: gather2 (h2 [n][48]) + {W2_o1+relu, W2_o2} -> fp32 out [n][40].
// Reads the CSR shadow in ws (d_out is being overwritten by this kernel).
// ---------------------------------------------------------------------------
__global__ __launch_bounds__(256)
void gchainC_kernel(const int* __restrict__ rowptr_end, const int* __restrict__ deg_g,
                    const int* __restrict__ eidx, const unsigned short* __restrict__ h2,
                    const unsigned short* __restrict__ wo1, const float* __restrict__ bo1,
                    const unsigned short* __restrict__ wo2, const float* __restrict__ bo2,
                    float* __restrict__ out, int n)
{
    __shared__ unsigned short slabA[16 * SLB];
    __shared__ unsigned short slabB[16 * SLB];
    const int t = threadIdx.x, wave = t >> 6, lane = t & 63;
    const int quad = lane >> 4, l16 = lane & 15;
    const int node0 = blockIdx.x * 16;

    // zero pad cols 48..63 of both slabs (gather writes only cols 0..47)
    for (int i = t; i < 16 * 16; i += 256) {
        int rr = i >> 4, cc = i & 15;
        slabA[rr * SLB + 48 + cc] = 0;
        slabB[rr * SLB + 48 + cc] = 0;
    }

    gather_relu_slab<S2, 12>(rowptr_end, deg_g, eidx, h2, slabA, node0, n, wave, quad, l16);
    __syncthreads();

    if (wave < 3) {   // @W2_o1 + b, relu -> slabB (cols 40..47 explicit 0)
        int o = wave * 16 + l16;
        f32x4 acc = mv16(slabA, wo1, o, l16, quad);
        float bv = (o < CD) ? bo1[o] : 0.f;
#pragma unroll
        for (int r = 0; r < 4; ++r) {
            float v = (o < CD) ? fmaxf(acc[r] + bv, 0.f) : 0.f;
            slabB[(quad * 4 + r) * SLB + o] = f2b(v);
        }
    }
    __syncthreads();
    if (wave < 3) {   // @W2_o2 + b -> global fp32 [n][40]
        int o = wave * 16 + l16;
        f32x4 acc = mv16(slabB, wo2, o, l16, quad);
        if (o < CD) {
            float bv = bo2[o];
#pragma unroll
            for (int r = 0; r < 4; ++r) {
                int node = node0 + quad * 4 + r;
                if (node < n) out[(size_t)node * CD + o] = acc[r] + bv;
            }
        }
    }
}

extern "C" void kernel_launch(void* const* d_in, const int* in_sizes, int n_in,
                              void* d_out, int out_size, void* d_ws, size_t ws_size,
                              hipStream_t stream)
{
    const float* x      = (const float*)d_in[0];
    const int*   ei     = (const int*)d_in[1];
    const float* w1_lin = (const float*)d_in[2];
    const float* b1_lin = (const float*)d_in[3];
    const float* w1_o1  = (const float*)d_in[4];
    const float* b1_o1  = (const float*)d_in[5];
    const float* w1_o2  = (const float*)d_in[6];
    const float* b1_o2  = (const float*)d_in[7];
    const float* w2_lin = (const float*)d_in[8];
    const float* b2_lin = (const float*)d_in[9];
    const float* w2_o1  = (const float*)d_in[10];
    const float* b2_o1  = (const float*)d_in[11];
    const float* w2_o2  = (const float*)d_in[12];
    const float* b2_o2  = (const float*)d_in[13];

    const int n = in_sizes[0] / FIN;   // 100000
    const int e = in_sizes[1] / 2;     // 1000000
    const int* src = ei;
    const int* dst = ei + e;

    // ---- d_ws layout (30.5 MB total, < R1's proven 33.8 MB) ----
    unsigned short* ws0 = (unsigned short*)d_ws;          // h1 [n][64]  12.8 MB
    unsigned short* ws2 = ws0 + (size_t)n * HD;           // h2 [n][48]   9.6 MB
    unsigned short* wb  = ws2 + (size_t)n * S2;
    unsigned short* wb1_lin = wb;                 // [64][128]
    unsigned short* wb1_o1  = wb1_lin + 64 * 128; // [64][64]
    unsigned short* wb1_o2  = wb1_o1  + 64 * 64;  // [64][64]
    unsigned short* wb2_lin = wb1_o2  + 64 * 64;  // [48][64]
    unsigned short* wb2_o1  = wb2_lin + 48 * 64;  // [48][64]
    unsigned short* wb2_o2  = wb2_o1  + 48 * 64;  // [48][64]
    uint2* pairs        = (uint2*)(wb2_o2 + 48 * 64);     // 8 MB; dead after bbuild
    int*   bucketCount  = (int*)(pairs + e);
    int*   bucketOff    = bucketCount + NBMAX;            // nb+1 entries
    int*   bucketCursor = bucketOff + NBMAX + 1;
    float* outp = (float*)d_out;

    // CSR arrays in d_out (R1-proven): built by bbuild, read by gchainB;
    // shadow-copied into the pairs region for gchainC.
    int* eidx   = (int*)d_out;
    int* deg    = eidx + e;
    int* rowptr = deg + n;
    int* ceidx   = (int*)pairs;       // CSR shadow (e+2n ints, contiguous)
    int* cdeg    = ceidx + e;
    int* crowptr = cdeg + n;

    const int nb    = (n + 255) >> 8;             // 391 buckets
    const int agrid = (e + ACH - 1) / ACH;        // 245 blocks
    const int tgrid = (n + 63) / 64;              // 1563 blocks
    const int ggrid = (n + 15) / 16;              // 6250 blocks
    const int cgrid = 150;                        // CSR-copy rider blocks
    const int c4    = (e + 2 * n) / 4;            // int4 count (e,n mult of 4)

    // 1. weights + bucketCount zero
    prep_kernel<<<(25600 + 255) / 256, 256, 0, stream>>>(
        w1_lin, w1_o1, w1_o2, w2_lin, w2_o1, w2_o2, wb, bucketCount);

    // 2. conv1-lin mv + bhist fused
    mv1_bhist_kernel<<<tgrid + agrid, 256, 0, stream>>>(
        x, wb1_lin, b1_lin, ws0, n, tgrid, dst, bucketCount, e, nb);

    // 3-5. CSR build (CSR -> d_out, as in verified R1)
    bscan_kernel<<<1, 256, 0, stream>>>(bucketCount, bucketOff, bucketCursor, nb);
    bpart_kernel<<<agrid, 256, 0, stream>>>(src, dst, bucketCursor, pairs, e, nb);
    bbuild_kernel<<<nb, 256, 0, stream>>>(pairs, bucketOff, rowptr, deg, eidx, n);

    // 6. gather1 + chainB fused -> ws2 [n][48]; rider copies CSR -> ws shadow
    gchainB_kernel<<<ggrid + cgrid, 256, 0, stream>>>(
        rowptr, deg, eidx, ws0, wb1_o1, b1_o1, wb1_o2, b1_o2, wb2_lin, b2_lin,
        ws2, n, ggrid, (const int4*)eidx, (int4*)ceidx, c4);

    // 7. gather2 + chainC fused -> out fp32 [n][40] (reads CSR shadow in ws)
    gchainC_kernel<<<ggrid, 256, 0, stream>>>(
        crowptr, cdeg, ceidx, ws2, wb2_o1, b2_o1, wb2_o2, b2_o2, outp, n);
}

// Round 8
// 241.871 us; speedup vs baseline: 1.0116x; 1.0116x over previous
//
#include <hip/hip_runtime.h>

static constexpr int FIN = 128;
static constexpr int HD  = 64;
static constexpr int CD  = 40;
static constexpr int S2  = 64;      // layer-2 node row stride: 128B line-aligned
static constexpr int SLB = 72;      // LDS slab stride (bf16), 64+8 pad

typedef __attribute__((ext_vector_type(8))) short short8;   // 8 bf16 = 4 VGPR
typedef __attribute__((ext_vector_type(4))) float f32x4;    // MFMA acc

__device__ __forceinline__ unsigned short f2b(float f)      // fp32->bf16 RNE
{
    union { float f; unsigned u; } x; x.f = f;
    unsigned u = x.u;
    return (unsigned short)((u + 0x7FFF + ((u >> 16) & 1)) >> 16);
}
__device__ __forceinline__ float b2f(unsigned short b)
{
    union { unsigned u; float f; } x; x.u = ((unsigned)b) << 16;
    return x.f;
}

static constexpr int NBMAX = 512;   // buckets of 256 nodes (n<=131072)
static constexpr int ACH   = 4096;  // edges per phase-A block

// ---------------------------------------------------------------------------
// prep: all 6 weight conversions (fp32 -> padded bf16) + zero bucketCount.
// ---------------------------------------------------------------------------
__global__ __launch_bounds__(256)
void prep_kernel(const float* __restrict__ w1_lin, const float* __restrict__ w1_o1,
                 const float* __restrict__ w1_o2, const float* __restrict__ w2_lin,
                 const float* __restrict__ w2_o1, const float* __restrict__ w2_o2,
                 unsigned short* __restrict__ wb, int* __restrict__ bucketCount)
{
    int i = blockIdx.x * 256 + threadIdx.x;
    if (i < NBMAX) bucketCount[i] = 0;
    if (i >= 25600) return;
    const float* src; int Kin, Kp, Oin, off;
    if (i < 8192)       { src = w1_lin; Kin = 128; Kp = 128; Oin = 64; off = 0; }
    else if (i < 12288) { src = w1_o1;  Kin = 64;  Kp = 64;  Oin = 64; off = 8192; }
    else if (i < 16384) { src = w1_o2;  Kin = 64;  Kp = 64;  Oin = 64; off = 12288; }
    else if (i < 19456) { src = w2_lin; Kin = 64;  Kp = 64;  Oin = 40; off = 16384; }
    else if (i < 22528) { src = w2_o1;  Kin = 40;  Kp = 64;  Oin = 40; off = 19456; }
    else                { src = w2_o2;  Kin = 40;  Kp = 64;  Oin = 40; off = 22528; }
    int j = i - off;
    int o = j / Kp, k = j - o * Kp;
    float v = (o < Oin && k < Kin) ? src[o * Kin + k] : 0.f;
    wb[i] = f2b(v);
}

// ---------------------------------------------------------------------------
// MFMA tile helper (verified index math) — used by mv1.
// ---------------------------------------------------------------------------
template<int NKT, int NOT>
__device__ __forceinline__ void mfma_tile(const short8* a, const unsigned short* __restrict__ Wbf,
                                          int l16, int quad, f32x4* acc)
{
    constexpr int KP = NKT * 32;
#pragma unroll
    for (int ot = 0; ot < NOT; ++ot) {
        acc[ot] = (f32x4){0.f, 0.f, 0.f, 0.f};
        const unsigned short* Wrow = Wbf + (size_t)(ot * 16 + l16) * KP + quad * 8;
#pragma unroll
        for (int kt = 0; kt < NKT; ++kt) {
            short8 b = *reinterpret_cast<const short8*>(Wrow + kt * 32);
            acc[ot] = __builtin_amdgcn_mfma_f32_16x16x32_bf16(a[kt], b, acc[ot], 0, 0, 0);
        }
    }
}

// per-wave single-output-slab matvec on a 16-row LDS slab (K=64)
__device__ __forceinline__ f32x4 mv16(const unsigned short* slab,
                                      const unsigned short* __restrict__ Wbf,
                                      int o, int l16, int quad)
{
    short8 a0 = *reinterpret_cast<const short8*>(&slab[l16 * SLB + quad * 8]);
    short8 a1 = *reinterpret_cast<const short8*>(&slab[l16 * SLB + 32 + quad * 8]);
    const unsigned short* Wrow = Wbf + (size_t)o * 64 + quad * 8;
    short8 b0 = *reinterpret_cast<const short8*>(Wrow);
    short8 b1 = *reinterpret_cast<const short8*>(Wrow + 32);
    f32x4 acc = (f32x4){0.f, 0.f, 0.f, 0.f};
    acc = __builtin_amdgcn_mfma_f32_16x16x32_bf16(a0, b0, acc, 0, 0, 0);
    acc = __builtin_amdgcn_mfma_f32_16x16x32_bf16(a1, b1, acc, 0, 0, 0);
    return acc;
}

// ---------------------------------------------------------------------------
// Fused conv1-lin mv + bhist (R1 verbatim: 256-node buckets, dst>>8).
// ---------------------------------------------------------------------------
__global__ __launch_bounds__(256)
void mv1_bhist_kernel(const float* __restrict__ x, const unsigned short* __restrict__ wb1_lin,
                      const float* __restrict__ b1_lin, unsigned short* __restrict__ h,
                      int n, int tgrid,
                      const int* __restrict__ dst, int* __restrict__ bucketCount, int e, int nb)
{
    __shared__ int cnt[NBMAX];
    if (blockIdx.x >= tgrid) {
        const int bb = blockIdx.x - tgrid;
        const int t = threadIdx.x;
        for (int j = t; j < nb; j += 256) cnt[j] = 0;
        __syncthreads();
        const int i0 = bb * ACH;
        const int i1 = min(e, i0 + ACH);
        for (int i = i0 + t; i < i1; i += 256)
            atomicAdd(&cnt[dst[i] >> 8], 1);
        __syncthreads();
        for (int j = t; j < nb; j += 256)
            if (cnt[j]) atomicAdd(&bucketCount[j], cnt[j]);
        return;
    }
    const int t = threadIdx.x, wave = t >> 6, lane = t & 63;
    const int quad = lane >> 4, l16 = lane & 15;
    const int n0 = blockIdx.x * 64, m0 = wave * 16;
    int row = n0 + m0 + l16; if (row >= n) row = n - 1;

    short8 a[4];
#pragma unroll
    for (int kt = 0; kt < 4; ++kt) {
        const float* p = x + (size_t)row * FIN + kt * 32 + quad * 8;
        float4 f0 = *reinterpret_cast<const float4*>(p);
        float4 f1 = *reinterpret_cast<const float4*>(p + 4);
        short8 v;
        v[0] = (short)f2b(f0.x); v[1] = (short)f2b(f0.y);
        v[2] = (short)f2b(f0.z); v[3] = (short)f2b(f0.w);
        v[4] = (short)f2b(f1.x); v[5] = (short)f2b(f1.y);
        v[6] = (short)f2b(f1.z); v[7] = (short)f2b(f1.w);
        a[kt] = v;
    }
    f32x4 acc[4];
    mfma_tile<4, 4>(a, wb1_lin, l16, quad, acc);
#pragma unroll
    for (int ot = 0; ot < 4; ++ot) {
        int o = ot * 16 + l16;
        float bv = b1_lin[o];
#pragma unroll
        for (int r = 0; r < 4; ++r) {
            int node = n0 + m0 + quad * 4 + r;
            if (node < n) h[(size_t)node * HD + o] = f2b(acc[ot][r] + bv);
        }
    }
}

// ---------------------------------------------------------------------------
// CSR build (R1 verbatim: 256-node buckets).
// ---------------------------------------------------------------------------
__global__ __launch_bounds__(256)
void bscan_kernel(const int* __restrict__ bucketCount, int* __restrict__ bucketOff,
                  int* __restrict__ bucketCursor, int nb)
{
    __shared__ int sA[NBMAX], sB[NBMAX];
    const int t = threadIdx.x;
#pragma unroll
    for (int s = t; s < NBMAX; s += 256) sA[s] = (s < nb) ? bucketCount[s] : 0;
    __syncthreads();
    int* pa = sA; int* pb = sB;
    for (int off = 1; off < NBMAX; off <<= 1) {
#pragma unroll
        for (int s = t; s < NBMAX; s += 256)
            pb[s] = pa[s] + ((s >= off) ? pa[s - off] : 0);
        __syncthreads();
        int* tmp = pa; pa = pb; pb = tmp;
    }
#pragma unroll
    for (int s = t; s <= nb && s < NBMAX; s += 256) {
        int v = (s == 0) ? 0 : pa[s - 1];
        bucketOff[s] = v;
        if (s < nb) bucketCursor[s] = v;
    }
}

__global__ __launch_bounds__(256)
void bpart_kernel(const int* __restrict__ src, const int* __restrict__ dst,
                  int* __restrict__ bucketCursor, uint2* __restrict__ pairs,
                  int e, int nb)
{
    __shared__ int cnt[NBMAX];
    __shared__ int base[NBMAX];
    const int t = threadIdx.x;
    for (int j = t; j < nb; j += 256) cnt[j] = 0;
    __syncthreads();
    const int i0 = blockIdx.x * ACH;
    const int i1 = min(e, i0 + ACH);
    for (int i = i0 + t; i < i1; i += 256)
        atomicAdd(&cnt[dst[i] >> 8], 1);
    __syncthreads();
    for (int j = t; j < nb; j += 256) {
        int c = cnt[j];
        base[j] = c ? atomicAdd(&bucketCursor[j], c) : 0;
        cnt[j] = 0;
    }
    __syncthreads();
    for (int i = i0 + t; i < i1; i += 256) {
        int d = dst[i];
        int bkt = d >> 8;
        int pos = base[bkt] + atomicAdd(&cnt[bkt], 1);
        pairs[pos] = make_uint2((unsigned)d, (unsigned)src[i]);
    }
}

__global__ __launch_bounds__(256)
void bbuild_kernel(const uint2* __restrict__ pairs, const int* __restrict__ bucketOff,
                   int* __restrict__ rowptr_end, int* __restrict__ deg_g,
                   int* __restrict__ eidx, int n)
{
    __shared__ int deg[256], sA[256], sB[256], cur[256];
    const int t = threadIdx.x;
    const int b = blockIdx.x;
    const int node0 = b << 8;
    const int e0 = bucketOff[b], e1 = bucketOff[b + 1];

    deg[t] = 0;
    __syncthreads();
    for (int i = e0 + t; i < e1; i += 256)
        atomicAdd(&deg[pairs[i].x & 255], 1);
    __syncthreads();
    sA[t] = deg[t];
    __syncthreads();
    int* pa = sA; int* pb = sB;
    for (int off = 1; off < 256; off <<= 1) {
        pb[t] = pa[t] + ((t >= off) ? pa[t - off] : 0);
        __syncthreads();
        int* tmp = pa; pa = pb; pb = tmp;
    }
    const int node = node0 + t;
    if (node < n) {
        rowptr_end[node] = e0 + pa[t];
        deg_g[node] = deg[t];
    }
    cur[t] = pa[t] - deg[t];
    __syncthreads();
    for (int i = e0 + t; i < e1; i += 256) {
        uint2 p = pairs[i];
        int pos = e0 + atomicAdd(&cur[p.x & 255], 1);
        eidx[pos] = (int)p.y;
    }
}

// ---------------------------------------------------------------------------
// gather phase (R6-proven: 4-deep manual unroll; 16 lanes per node).
// Summation order unchanged (adds in j order). Result relu'd into slabA.
// ---------------------------------------------------------------------------
template<int STRIDE, int LPN>
__device__ __forceinline__ void gather_relu_slab(
    const int* __restrict__ rowptr_end, const int* __restrict__ deg_g,
    const int* __restrict__ eidx, const unsigned short* __restrict__ h,
    unsigned short* slabA, int node0, int n, int wave, int grp, int l16)
{
    const int r16 = wave * 4 + grp;
    const int node = node0 + r16;
    const int nodec = (node < n) ? node : (n - 1);
    const bool act = (l16 < LPN);
    const int c0 = l16 * 4;
    const int g16 = grp * 16;

    float a0 = 0.f, a1 = 0.f, a2 = 0.f, a3 = 0.f;
    if (act) {
        ushort4 v = *reinterpret_cast<const ushort4*>(h + (size_t)nodec * STRIDE + c0);
        a0 = b2f(v.x); a1 = b2f(v.y); a2 = b2f(v.z); a3 = b2f(v.w);
    }
    int end   = rowptr_end[nodec];
    int start = end - deg_g[nodec];
    if (node >= n) end = start;

    for (int base = start; base < end; base += 16) {
        int m = min(16, end - base);
        int sv = (l16 < m) ? eidx[base + l16] : 0;
        int j = 0;
        for (; j + 4 <= m; j += 4) {
            int s0 = __shfl(sv, g16 + j,     64);
            int s1 = __shfl(sv, g16 + j + 1, 64);
            int s2 = __shfl(sv, g16 + j + 2, 64);
            int s3 = __shfl(sv, g16 + j + 3, 64);
            if (act) {
                ushort4 w0 = *reinterpret_cast<const ushort4*>(h + (size_t)s0 * STRIDE + c0);
                ushort4 w1 = *reinterpret_cast<const ushort4*>(h + (size_t)s1 * STRIDE + c0);
                ushort4 w2 = *reinterpret_cast<const ushort4*>(h + (size_t)s2 * STRIDE + c0);
                ushort4 w3 = *reinterpret_cast<const ushort4*>(h + (size_t)s3 * STRIDE + c0);
                a0 += b2f(w0.x); a1 += b2f(w0.y); a2 += b2f(w0.z); a3 += b2f(w0.w);
                a0 += b2f(w1.x); a1 += b2f(w1.y); a2 += b2f(w1.z); a3 += b2f(w1.w);
                a0 += b2f(w2.x); a1 += b2f(w2.y); a2 += b2f(w2.z); a3 += b2f(w2.w);
                a0 += b2f(w3.x); a1 += b2f(w3.y); a2 += b2f(w3.z); a3 += b2f(w3.w);
            }
        }
        for (; j < m; ++j) {
            int s = __shfl(sv, g16 + j, 64);
            if (act) {
                ushort4 v = *reinterpret_cast<const ushort4*>(h + (size_t)s * STRIDE + c0);
                a0 += b2f(v.x); a1 += b2f(v.y); a2 += b2f(v.z); a3 += b2f(v.w);
            }
        }
    }
    if (act) {
        ushort4 o;
        o.x = f2b(fmaxf(a0, 0.f)); o.y = f2b(fmaxf(a1, 0.f));
        o.z = f2b(fmaxf(a2, 0.f)); o.w = f2b(fmaxf(a3, 0.f));
        *reinterpret_cast<ushort4*>(&slabA[r16 * SLB + c0]) = o;
    }
}

// ---------------------------------------------------------------------------
// gchainB: gather1 (h [n][64]) + {W1_o1+relu, W1_o2+relu, W2_lin} -> bf16 [n][64].
// Cols 40..63 of each output row are zero (line-aligned rows for gather2).
// Rider blocks [ggrid, ggrid+cgrid): CSR shadow copy d_out -> ws (pairs region).
// ---------------------------------------------------------------------------
__global__ __launch_bounds__(256)
void gchainB_kernel(const int* __restrict__ rowptr_end, const int* __restrict__ deg_g,
                    const int* __restrict__ eidx, const unsigned short* __restrict__ h,
                    const unsigned short* __restrict__ wo1, const float* __restrict__ bo1,
                    const unsigned short* __restrict__ wo2, const float* __restrict__ bo2,
                    const unsigned short* __restrict__ wlin, const float* __restrict__ blin,
                    unsigned short* __restrict__ out, int n, int ggrid,
                    const int4* __restrict__ csr_src, int4* __restrict__ csr_dst, int c4)
{
    if (blockIdx.x >= ggrid) {           // CSR shadow-copy rider (read-read on d_out)
        const int stride = (gridDim.x - ggrid) * 256;
        for (int i = (blockIdx.x - ggrid) * 256 + threadIdx.x; i < c4; i += stride)
            csr_dst[i] = csr_src[i];
        return;
    }

    __shared__ unsigned short slabA[16 * SLB];
    __shared__ unsigned short slabB[16 * SLB];
    const int t = threadIdx.x, wave = t >> 6, lane = t & 63;
    const int quad = lane >> 4, l16 = lane & 15;
    const int node0 = blockIdx.x * 16;

    gather_relu_slab<HD, 16>(rowptr_end, deg_g, eidx, h, slabA, node0, n, wave, quad, l16);
    __syncthreads();

    {   // @W1_o1 + b, relu -> slabB
        int o = wave * 16 + l16;
        f32x4 acc = mv16(slabA, wo1, o, l16, quad);
        float bv = bo1[o];
#pragma unroll
        for (int r = 0; r < 4; ++r)
            slabB[(quad * 4 + r) * SLB + o] = f2b(fmaxf(acc[r] + bv, 0.f));
    }
    __syncthreads();
    {   // @W1_o2 + b, top-level relu -> slabA
        int o = wave * 16 + l16;
        f32x4 acc = mv16(slabB, wo2, o, l16, quad);
        float bv = bo2[o];
#pragma unroll
        for (int r = 0; r < 4; ++r)
            slabA[(quad * 4 + r) * SLB + o] = f2b(fmaxf(acc[r] + bv, 0.f));
    }
    __syncthreads();
    if (wave < 3) {   // @W2_lin + b -> global bf16 [n][64], cols 40..47 = 0
        int o = wave * 16 + l16;
        f32x4 acc = mv16(slabA, wlin, o, l16, quad);
        float bv = (o < CD) ? blin[o] : 0.f;
#pragma unroll
        for (int r = 0; r < 4; ++r) {
            int node = node0 + quad * 4 + r;
            if (node < n) {
                float v = (o < CD) ? (acc[r] + bv) : 0.f;
                out[(size_t)node * S2 + o] = f2b(v);
            }
        }
    }
    else {            // wave 3: cols 48..63 = 0 (wlin has only 48 rows — no MFMA)
        int o = 48 + l16;
#pragma unroll
        for (int r = 0; r < 4; ++r) {
            int node = node0 + quad * 4 + r;
            if (node < n) out[(size_t)node * S2 + o] = 0;
        }
    }
}

// ---------------------------------------------------------------------------
// gchainC: gather2 (h2 [n][64], cols 40..63 zero) + {W2_o1+relu, W2_o2}
// -> fp32 out [n][40]. Reads the CSR shadow in ws (d_out being overwritten).
// ---------------------------------------------------------------------------
__global__ __launch_bounds__(256)
void gchainC_kernel(const int* __restrict__ rowptr_end, const int* __restrict__ deg_g,
                    const int* __restrict__ eidx, const unsigned short* __restrict__ h2,
                    const unsigned short* __restrict__ wo1, const float* __restrict__ bo1,
                    const unsigned short* __restrict__ wo2, const float* __restrict__ bo2,
                    float* __restrict__ out, int n)
{
    __shared__ unsigned short slabA[16 * SLB];
    __shared__ unsigned short slabB[16 * SLB];
    const int t = threadIdx.x, wave = t >> 6, lane = t & 63;
    const int quad = lane >> 4, l16 = lane & 15;
    const int node0 = blockIdx.x * 16;

    // zero pad cols 48..63 of both slabs (gather writes only cols 0..47)
    for (int i = t; i < 16 * 16; i += 256) {
        int rr = i >> 4, cc = i & 15;
        slabA[rr * SLB + 48 + cc] = 0;
        slabB[rr * SLB + 48 + cc] = 0;
    }

    gather_relu_slab<S2, 12>(rowptr_end, deg_g, eidx, h2, slabA, node0, n, wave, quad, l16);
    __syncthreads();

    if (wave < 3) {   // @W2_o1 + b, relu -> slabB (cols 40..47 explicit 0)
        int o = wave * 16 + l16;
        f32x4 acc = mv16(slabA, wo1, o, l16, quad);
        float bv = (o < CD) ? bo1[o] : 0.f;
#pragma unroll
        for (int r = 0; r < 4; ++r) {
            float v = (o < CD) ? fmaxf(acc[r] + bv, 0.f) : 0.f;
            slabB[(quad * 4 + r) * SLB + o] = f2b(v);
        }
    }
    __syncthreads();
    if (wave < 3) {   // @W2_o2 + b -> global fp32 [n][40]
        int o = wave * 16 + l16;
        f32x4 acc = mv16(slabB, wo2, o, l16, quad);
        if (o < CD) {
            float bv = bo2[o];
#pragma unroll
            for (int r = 0; r < 4; ++r) {
                int node = node0 + quad * 4 + r;
                if (node < n) out[(size_t)node * CD + o] = acc[r] + bv;
            }
        }
    }
}

extern "C" void kernel_launch(void* const* d_in, const int* in_sizes, int n_in,
                              void* d_out, int out_size, void* d_ws, size_t ws_size,
                              hipStream_t stream)
{
    const float* x      = (const float*)d_in[0];
    const int*   ei     = (const int*)d_in[1];
    const float* w1_lin = (const float*)d_in[2];
    const float* b1_lin = (const float*)d_in[3];
    const float* w1_o1  = (const float*)d_in[4];
    const float* b1_o1  = (const float*)d_in[5];
    const float* w1_o2  = (const float*)d_in[6];
    const float* b1_o2  = (const float*)d_in[7];
    const float* w2_lin = (const float*)d_in[8];
    const float* b2_lin = (const float*)d_in[9];
    const float* w2_o1  = (const float*)d_in[10];
    const float* b2_o1  = (const float*)d_in[11];
    const float* w2_o2  = (const float*)d_in[12];
    const float* b2_o2  = (const float*)d_in[13];

    const int n = in_sizes[0] / FIN;   // 100000
    const int e = in_sizes[1] / 2;     // 1000000
    const int* src = ei;
    const int* dst = ei + e;

    // ---- d_ws layout (33.66 MB total == R1's proven footprint) ----
    unsigned short* ws0 = (unsigned short*)d_ws;          // h1 [n][64]  12.8 MB
    unsigned short* ws2 = ws0 + (size_t)n * HD;           // h2 [n][64]  12.8 MB
    unsigned short* wb  = ws2 + (size_t)n * S2;
    unsigned short* wb1_lin = wb;                 // [64][128]
    unsigned short* wb1_o1  = wb1_lin + 64 * 128; // [64][64]
    unsigned short* wb1_o2  = wb1_o1  + 64 * 64;  // [64][64]
    unsigned short* wb2_lin = wb1_o2  + 64 * 64;  // [48][64]
    unsigned short* wb2_o1  = wb2_lin + 48 * 64;  // [48][64]
    unsigned short* wb2_o2  = wb2_o1  + 48 * 64;  // [48][64]
    uint2* pairs        = (uint2*)(wb2_o2 + 48 * 64);     // 8 MB; dead after bbuild
    int*   bucketCount  = (int*)(pairs + e);
    int*   bucketOff    = bucketCount + NBMAX;            // nb+1 entries
    int*   bucketCursor = bucketOff + NBMAX + 1;
    float* outp = (float*)d_out;

    // CSR arrays in d_out (R1-proven): built by bbuild, read by gchainB;
    // shadow-copied into the pairs region for gchainC.
    int* eidx   = (int*)d_out;
    int* deg    = eidx + e;
    int* rowptr = deg + n;
    int* ceidx   = (int*)pairs;       // CSR shadow (e+2n ints, contiguous)
    int* cdeg    = ceidx + e;
    int* crowptr = cdeg + n;

    const int nb    = (n + 255) >> 8;             // 391 buckets
    const int agrid = (e + ACH - 1) / ACH;        // 245 blocks
    const int tgrid = (n + 63) / 64;              // 1563 blocks
    const int ggrid = (n + 15) / 16;              // 6250 blocks
    const int cgrid = 150;                        // CSR-copy rider blocks
    const int c4    = (e + 2 * n) / 4;            // int4 count (e,n mult of 4)

    // 1. weights + bucketCount zero
    prep_kernel<<<(25600 + 255) / 256, 256, 0, stream>>>(
        w1_lin, w1_o1, w1_o2, w2_lin, w2_o1, w2_o2, wb, bucketCount);

    // 2. conv1-lin mv + bhist fused
    mv1_bhist_kernel<<<tgrid + agrid, 256, 0, stream>>>(
        x, wb1_lin, b1_lin, ws0, n, tgrid, dst, bucketCount, e, nb);

    // 3-5. CSR build (CSR -> d_out, as in verified R1)
    bscan_kernel<<<1, 256, 0, stream>>>(bucketCount, bucketOff, bucketCursor, nb);
    bpart_kernel<<<agrid, 256, 0, stream>>>(src, dst, bucketCursor, pairs, e, nb);
    bbuild_kernel<<<nb, 256, 0, stream>>>(pairs, bucketOff, rowptr, deg, eidx, n);

    // 6. gather1 + chainB fused -> ws2 [n][64]; rider copies CSR -> ws shadow
    gchainB_kernel<<<ggrid + cgrid, 256, 0, stream>>>(
        rowptr, deg, eidx, ws0, wb1_o1, b1_o1, wb1_o2, b1_o2, wb2_lin, b2_lin,
        ws2, n, ggrid, (const int4*)eidx, (int4*)ceidx, c4);

    // 7. gather2 + chainC fused -> out fp32 [n][40] (reads CSR shadow in ws)
    gchainC_kernel<<<ggrid, 256, 0, stream>>>(
        crowptr, cdeg, ceidx, ws2, wb2_o1, b2_o1, wb2_o2, b2_o2, outp, n);
}

// Round 9
// 240.362 us; speedup vs baseline: 1.0180x; 1.0063x over previous
//
#include <hip/hip_runtime.h>

static constexpr int FIN = 128;
static constexpr int HD  = 64;
static constexpr int CD  = 40;
static constexpr int S2  = 64;      // layer-2 node row stride: 128B line-aligned
static constexpr int SLB = 72;      // LDS slab stride (bf16), 64+8 pad

typedef __attribute__((ext_vector_type(8))) short short8;   // 8 bf16 = 4 VGPR
typedef __attribute__((ext_vector_type(4))) float f32x4;    // MFMA acc

__device__ __forceinline__ unsigned short f2b(float f)      // fp32->bf16 RNE
{
    union { float f; unsigned u; } x; x.f = f;
    unsigned u = x.u;
    return (unsigned short)((u + 0x7FFF + ((u >> 16) & 1)) >> 16);
}
__device__ __forceinline__ float b2f(unsigned short b)
{
    union { unsigned u; float f; } x; x.u = ((unsigned)b) << 16;
    return x.f;
}

static constexpr int NBMAX = 512;   // buckets of 256 nodes (n<=131072)
static constexpr int ACH   = 4096;  // edges per phase-A block

// ---------------------------------------------------------------------------
// MFMA tile helper (verified index math) — used by mv1.
// ---------------------------------------------------------------------------
template<int NKT, int NOT>
__device__ __forceinline__ void mfma_tile(const short8* a, const unsigned short* __restrict__ Wbf,
                                          int l16, int quad, f32x4* acc)
{
    constexpr int KP = NKT * 32;
#pragma unroll
    for (int ot = 0; ot < NOT; ++ot) {
        acc[ot] = (f32x4){0.f, 0.f, 0.f, 0.f};
        const unsigned short* Wrow = Wbf + (size_t)(ot * 16 + l16) * KP + quad * 8;
#pragma unroll
        for (int kt = 0; kt < NKT; ++kt) {
            short8 b = *reinterpret_cast<const short8*>(Wrow + kt * 32);
            acc[ot] = __builtin_amdgcn_mfma_f32_16x16x32_bf16(a[kt], b, acc[ot], 0, 0, 0);
        }
    }
}

// per-wave single-output-slab matvec on a 16-row LDS slab (K=64)
__device__ __forceinline__ f32x4 mv16(const unsigned short* slab,
                                      const unsigned short* __restrict__ Wbf,
                                      int o, int l16, int quad)
{
    short8 a0 = *reinterpret_cast<const short8*>(&slab[l16 * SLB + quad * 8]);
    short8 a1 = *reinterpret_cast<const short8*>(&slab[l16 * SLB + 32 + quad * 8]);
    const unsigned short* Wrow = Wbf + (size_t)o * 64 + quad * 8;
    short8 b0 = *reinterpret_cast<const short8*>(Wrow);
    short8 b1 = *reinterpret_cast<const short8*>(Wrow + 32);
    f32x4 acc = (f32x4){0.f, 0.f, 0.f, 0.f};
    acc = __builtin_amdgcn_mfma_f32_16x16x32_bf16(a0, b0, acc, 0, 0, 0);
    acc = __builtin_amdgcn_mfma_f32_16x16x32_bf16(a1, b1, acc, 0, 0, 0);
    return acc;
}

// ---------------------------------------------------------------------------
// mv1 body (R8-verbatim math): conv1-lin on the 64-node slab vb.
// ---------------------------------------------------------------------------
__device__ __forceinline__ void mv1_body(const float* __restrict__ x,
    const unsigned short* __restrict__ wb1_lin, const float* __restrict__ b1_lin,
    unsigned short* __restrict__ h, int n, int vb)
{
    const int t = threadIdx.x, wave = t >> 6, lane = t & 63;
    const int quad = lane >> 4, l16 = lane & 15;
    const int n0 = vb * 64, m0 = wave * 16;
    int row = n0 + m0 + l16; if (row >= n) row = n - 1;

    short8 a[4];
#pragma unroll
    for (int kt = 0; kt < 4; ++kt) {
        const float* p = x + (size_t)row * FIN + kt * 32 + quad * 8;
        float4 f0 = *reinterpret_cast<const float4*>(p);
        float4 f1 = *reinterpret_cast<const float4*>(p + 4);
        short8 v;
        v[0] = (short)f2b(f0.x); v[1] = (short)f2b(f0.y);
        v[2] = (short)f2b(f0.z); v[3] = (short)f2b(f0.w);
        v[4] = (short)f2b(f1.x); v[5] = (short)f2b(f1.y);
        v[6] = (short)f2b(f1.z); v[7] = (short)f2b(f1.w);
        a[kt] = v;
    }
    f32x4 acc[4];
    mfma_tile<4, 4>(a, wb1_lin, l16, quad, acc);
#pragma unroll
    for (int ot = 0; ot < 4; ++ot) {
        int o = ot * 16 + l16;
        float bv = b1_lin[o];
#pragma unroll
        for (int r = 0; r < 4; ++r) {
            int node = n0 + m0 + quad * 4 + r;
            if (node < n) h[(size_t)node * HD + o] = f2b(acc[ot][r] + bv);
        }
    }
}

// ---------------------------------------------------------------------------
// prep (weight conversions) + bhist rider. bucketCount pre-zeroed by memset.
// Blocks [0, wgrid): weights. Blocks [wgrid, wgrid+agrid): bhist.
// ---------------------------------------------------------------------------
__global__ __launch_bounds__(256)
void prep_bhist_kernel(const float* __restrict__ w1_lin, const float* __restrict__ w1_o1,
                       const float* __restrict__ w1_o2, const float* __restrict__ w2_lin,
                       const float* __restrict__ w2_o1, const float* __restrict__ w2_o2,
                       unsigned short* __restrict__ wb, int wgrid,
                       const int* __restrict__ dst, int* __restrict__ bucketCount,
                       int e, int nb)
{
    __shared__ int cnt[NBMAX];
    if (blockIdx.x >= wgrid) {      // bhist rider
        const int bb = blockIdx.x - wgrid;
        const int t = threadIdx.x;
        for (int j = t; j < nb; j += 256) cnt[j] = 0;
        __syncthreads();
        const int i0 = bb * ACH;
        const int i1 = min(e, i0 + ACH);
        for (int i = i0 + t; i < i1; i += 256)
            atomicAdd(&cnt[dst[i] >> 8], 1);
        __syncthreads();
        for (int j = t; j < nb; j += 256)
            if (cnt[j]) atomicAdd(&bucketCount[j], cnt[j]);
        return;
    }
    int i = blockIdx.x * 256 + threadIdx.x;
    if (i >= 25600) return;
    const float* src; int Kin, Kp, Oin, off;
    if (i < 8192)       { src = w1_lin; Kin = 128; Kp = 128; Oin = 64; off = 0; }
    else if (i < 12288) { src = w1_o1;  Kin = 64;  Kp = 64;  Oin = 64; off = 8192; }
    else if (i < 16384) { src = w1_o2;  Kin = 64;  Kp = 64;  Oin = 64; off = 12288; }
    else if (i < 19456) { src = w2_lin; Kin = 64;  Kp = 64;  Oin = 40; off = 16384; }
    else if (i < 22528) { src = w2_o1;  Kin = 40;  Kp = 64;  Oin = 40; off = 19456; }
    else                { src = w2_o2;  Kin = 40;  Kp = 64;  Oin = 40; off = 22528; }
    int j = i - off;
    int o = j / Kp, k = j - o * Kp;
    float v = (o < Oin && k < Kin) ? src[o * Kin + k] : 0.f;
    wb[i] = f2b(v);
}

// ---------------------------------------------------------------------------
// bscan (R1 verbatim).
// ---------------------------------------------------------------------------
__global__ __launch_bounds__(256)
void bscan_kernel(const int* __restrict__ bucketCount, int* __restrict__ bucketOff,
                  int* __restrict__ bucketCursor, int nb)
{
    __shared__ int sA[NBMAX], sB[NBMAX];
    const int t = threadIdx.x;
#pragma unroll
    for (int s = t; s < NBMAX; s += 256) sA[s] = (s < nb) ? bucketCount[s] : 0;
    __syncthreads();
    int* pa = sA; int* pb = sB;
    for (int off = 1; off < NBMAX; off <<= 1) {
#pragma unroll
        for (int s = t; s < NBMAX; s += 256)
            pb[s] = pa[s] + ((s >= off) ? pa[s - off] : 0);
        __syncthreads();
        int* tmp = pa; pa = pb; pb = tmp;
    }
#pragma unroll
    for (int s = t; s <= nb && s < NBMAX; s += 256) {
        int v = (s == 0) ? 0 : pa[s - 1];
        bucketOff[s] = v;
        if (s < nb) bucketCursor[s] = v;
    }
}

// ---------------------------------------------------------------------------
// bpart (R1 verbatim) + mv1 rider: blocks [agrid, ...) run mv1 slabs
// [0, mv1cnt) — mv1 is independent of the CSR chain, so it overlaps here.
// ---------------------------------------------------------------------------
__global__ __launch_bounds__(256)
void bpart_mv1_kernel(const int* __restrict__ src, const int* __restrict__ dst,
                      int* __restrict__ bucketCursor, uint2* __restrict__ pairs,
                      int e, int nb, int agrid,
                      const float* __restrict__ x, const unsigned short* __restrict__ wb1_lin,
                      const float* __restrict__ b1_lin, unsigned short* __restrict__ h, int n)
{
    __shared__ int cnt[NBMAX];
    __shared__ int base[NBMAX];
    if (blockIdx.x >= agrid) {      // mv1 rider
        mv1_body(x, wb1_lin, b1_lin, h, n, blockIdx.x - agrid);
        return;
    }
    const int t = threadIdx.x;
    for (int j = t; j < nb; j += 256) cnt[j] = 0;
    __syncthreads();
    const int i0 = blockIdx.x * ACH;
    const int i1 = min(e, i0 + ACH);
    for (int i = i0 + t; i < i1; i += 256)
        atomicAdd(&cnt[dst[i] >> 8], 1);
    __syncthreads();
    for (int j = t; j < nb; j += 256) {
        int c = cnt[j];
        base[j] = c ? atomicAdd(&bucketCursor[j], c) : 0;
        cnt[j] = 0;
    }
    __syncthreads();
    for (int i = i0 + t; i < i1; i += 256) {
        int d = dst[i];
        int bkt = d >> 8;
        int pos = base[bkt] + atomicAdd(&cnt[bkt], 1);
        pairs[pos] = make_uint2((unsigned)d, (unsigned)src[i]);
    }
}

// ---------------------------------------------------------------------------
// bbuild (R1 verbatim) + mv1 rider: blocks [nb, ...) run mv1 slabs
// [mv1base, tgrid).
// ---------------------------------------------------------------------------
__global__ __launch_bounds__(256)
void bbuild_mv1_kernel(const uint2* __restrict__ pairs, const int* __restrict__ bucketOff,
                       int* __restrict__ rowptr_end, int* __restrict__ deg_g,
                       int* __restrict__ eidx, int n, int nb, int mv1base,
                       const float* __restrict__ x, const unsigned short* __restrict__ wb1_lin,
                       const float* __restrict__ b1_lin, unsigned short* __restrict__ h)
{
    __shared__ int deg[256], sA[256], sB[256], cur[256];
    if (blockIdx.x >= nb) {         // mv1 rider
        mv1_body(x, wb1_lin, b1_lin, h, n, mv1base + (int)blockIdx.x - nb);
        return;
    }
    const int t = threadIdx.x;
    const int b = blockIdx.x;
    const int node0 = b << 8;
    const int e0 = bucketOff[b], e1 = bucketOff[b + 1];

    deg[t] = 0;
    __syncthreads();
    for (int i = e0 + t; i < e1; i += 256)
        atomicAdd(&deg[pairs[i].x & 255], 1);
    __syncthreads();
    sA[t] = deg[t];
    __syncthreads();
    int* pa = sA; int* pb = sB;
    for (int off = 1; off < 256; off <<= 1) {
        pb[t] = pa[t] + ((t >= off) ? pa[t - off] : 0);
        __syncthreads();
        int* tmp = pa; pa = pb; pb = tmp;
    }
    const int node = node0 + t;
    if (node < n) {
        rowptr_end[node] = e0 + pa[t];
        deg_g[node] = deg[t];
    }
    cur[t] = pa[t] - deg[t];
    __syncthreads();
    for (int i = e0 + t; i < e1; i += 256) {
        uint2 p = pairs[i];
        int pos = e0 + atomicAdd(&cur[p.x & 255], 1);
        eidx[pos] = (int)p.y;
    }
}

// ---------------------------------------------------------------------------
// gather phase (R6-proven: 4-deep manual unroll; 16 lanes per node).
// Summation order unchanged (adds in j order). Result relu'd into slabA.
// ---------------------------------------------------------------------------
template<int STRIDE, int LPN>
__device__ __forceinline__ void gather_relu_slab(
    const int* __restrict__ rowptr_end, const int* __restrict__ deg_g,
    const int* __restrict__ eidx, const unsigned short* __restrict__ h,
    unsigned short* slabA, int node0, int n, int wave, int grp, int l16)
{
    const int r16 = wave * 4 + grp;
    const int node = node0 + r16;
    const int nodec = (node < n) ? node : (n - 1);
    const bool act = (l16 < LPN);
    const int c0 = l16 * 4;
    const int g16 = grp * 16;

    float a0 = 0.f, a1 = 0.f, a2 = 0.f, a3 = 0.f;
    if (act) {
        ushort4 v = *reinterpret_cast<const ushort4*>(h + (size_t)nodec * STRIDE + c0);
        a0 = b2f(v.x); a1 = b2f(v.y); a2 = b2f(v.z); a3 = b2f(v.w);
    }
    int end   = rowptr_end[nodec];
    int start = end - deg_g[nodec];
    if (node >= n) end = start;

    for (int base = start; base < end; base += 16) {
        int m = min(16, end - base);
        int sv = (l16 < m) ? eidx[base + l16] : 0;
        int j = 0;
        for (; j + 4 <= m; j += 4) {
            int s0 = __shfl(sv, g16 + j,     64);
            int s1 = __shfl(sv, g16 + j + 1, 64);
            int s2 = __shfl(sv, g16 + j + 2, 64);
            int s3 = __shfl(sv, g16 + j + 3, 64);
            if (act) {
                ushort4 w0 = *reinterpret_cast<const ushort4*>(h + (size_t)s0 * STRIDE + c0);
                ushort4 w1 = *reinterpret_cast<const ushort4*>(h + (size_t)s1 * STRIDE + c0);
                ushort4 w2 = *reinterpret_cast<const ushort4*>(h + (size_t)s2 * STRIDE + c0);
                ushort4 w3 = *reinterpret_cast<const ushort4*>(h + (size_t)s3 * STRIDE + c0);
                a0 += b2f(w0.x); a1 += b2f(w0.y); a2 += b2f(w0.z); a3 += b2f(w0.w);
                a0 += b2f(w1.x); a1 += b2f(w1.y); a2 += b2f(w1.z); a3 += b2f(w1.w);
                a0 += b2f(w2.x); a1 += b2f(w2.y); a2 += b2f(w2.z); a3 += b2f(w2.w);
                a0 += b2f(w3.x); a1 += b2f(w3.y); a2 += b2f(w3.z); a3 += b2f(w3.w);
            }
        }
        for (; j < m; ++j) {
            int s = __shfl(sv, g16 + j, 64);
            if (act) {
                ushort4 v = *reinterpret_cast<const ushort4*>(h + (size_t)s * STRIDE + c0);
                a0 += b2f(v.x); a1 += b2f(v.y); a2 += b2f(v.z); a3 += b2f(v.w);
            }
        }
    }
    if (act) {
        ushort4 o;
        o.x = f2b(fmaxf(a0, 0.f)); o.y = f2b(fmaxf(a1, 0.f));
        o.z = f2b(fmaxf(a2, 0.f)); o.w = f2b(fmaxf(a3, 0.f));
        *reinterpret_cast<ushort4*>(&slabA[r16 * SLB + c0]) = o;
    }
}

// ---------------------------------------------------------------------------
// gchainB: gather1 (h [n][64]) + {W1_o1+relu, W1_o2+relu, W2_lin} -> bf16 [n][64].
// Cols 40..63 of each output row are zero (line-aligned rows for gather2).
// Rider blocks [ggrid, ggrid+cgrid): CSR shadow copy d_out -> ws (pairs region).
// ---------------------------------------------------------------------------
__global__ __launch_bounds__(256)
void gchainB_kernel(const int* __restrict__ rowptr_end, const int* __restrict__ deg_g,
                    const int* __restrict__ eidx, const unsigned short* __restrict__ h,
                    const unsigned short* __restrict__ wo1, const float* __restrict__ bo1,
                    const unsigned short* __restrict__ wo2, const float* __restrict__ bo2,
                    const unsigned short* __restrict__ wlin, const float* __restrict__ blin,
                    unsigned short* __restrict__ out, int n, int ggrid,
                    const int4* __restrict__ csr_src, int4* __restrict__ csr_dst, int c4)
{
    if (blockIdx.x >= ggrid) {           // CSR shadow-copy rider (read-read on d_out)
        const int stride = (gridDim.x - ggrid) * 256;
        for (int i = (blockIdx.x - ggrid) * 256 + threadIdx.x; i < c4; i += stride)
            csr_dst[i] = csr_src[i];
        return;
    }

    __shared__ unsigned short slabA[16 * SLB];
    __shared__ unsigned short slabB[16 * SLB];
    const int t = threadIdx.x, wave = t >> 6, lane = t & 63;
    const int quad = lane >> 4, l16 = lane & 15;
    const int node0 = blockIdx.x * 16;

    gather_relu_slab<HD, 16>(rowptr_end, deg_g, eidx, h, slabA, node0, n, wave, quad, l16);
    __syncthreads();

    {   // @W1_o1 + b, relu -> slabB
        int o = wave * 16 + l16;
        f32x4 acc = mv16(slabA, wo1, o, l16, quad);
        float bv = bo1[o];
#pragma unroll
        for (int r = 0; r < 4; ++r)
            slabB[(quad * 4 + r) * SLB + o] = f2b(fmaxf(acc[r] + bv, 0.f));
    }
    __syncthreads();
    {   // @W1_o2 + b, top-level relu -> slabA
        int o = wave * 16 + l16;
        f32x4 acc = mv16(slabB, wo2, o, l16, quad);
        float bv = bo2[o];
#pragma unroll
        for (int r = 0; r < 4; ++r)
            slabA[(quad * 4 + r) * SLB + o] = f2b(fmaxf(acc[r] + bv, 0.f));
    }
    __syncthreads();
    if (wave < 3) {   // @W2_lin + b -> global bf16 [n][64], cols 40..47 = 0
        int o = wave * 16 + l16;
        f32x4 acc = mv16(slabA, wlin, o, l16, quad);
        float bv = (o < CD) ? blin[o] : 0.f;
#pragma unroll
        for (int r = 0; r < 4; ++r) {
            int node = node0 + quad * 4 + r;
            if (node < n) {
                float v = (o < CD) ? (acc[r] + bv) : 0.f;
                out[(size_t)node * S2 + o] = f2b(v);
            }
        }
    }
    else {            // wave 3: cols 48..63 = 0 (wlin has only 48 rows — no MFMA)
        int o = 48 + l16;
#pragma unroll
        for (int r = 0; r < 4; ++r) {
            int node = node0 + quad * 4 + r;
            if (node < n) out[(size_t)node * S2 + o] = 0;
        }
    }
}

// ---------------------------------------------------------------------------
// gchainC: gather2 (h2 [n][64], cols 40..63 zero) + {W2_o1+relu, W2_o2}
// -> fp32 out [n][40]. Reads the CSR shadow in ws (d_out being overwritten).
// ---------------------------------------------------------------------------
__global__ __launch_bounds__(256)
void gchainC_kernel(const int* __restrict__ rowptr_end, const int* __restrict__ deg_g,
                    const int* __restrict__ eidx, const unsigned short* __restrict__ h2,
                    const unsigned short* __restrict__ wo1, const float* __restrict__ bo1,
                    const unsigned short* __restrict__ wo2, const float* __restrict__ bo2,
                    float* __restrict__ out, int n)
{
    __shared__ unsigned short slabA[16 * SLB];
    __shared__ unsigned short slabB[16 * SLB];
    const int t = threadIdx.x, wave = t >> 6, lane = t & 63;
    const int quad = lane >> 4, l16 = lane & 15;
    const int node0 = blockIdx.x * 16;

    // zero pad cols 48..63 of both slabs (gather writes only cols 0..47)
    for (int i = t; i < 16 * 16; i += 256) {
        int rr = i >> 4, cc = i & 15;
        slabA[rr * SLB + 48 + cc] = 0;
        slabB[rr * SLB + 48 + cc] = 0;
    }

    gather_relu_slab<S2, 12>(rowptr_end, deg_g, eidx, h2, slabA, node0, n, wave, quad, l16);
    __syncthreads();

    if (wave < 3) {   // @W2_o1 + b, relu -> slabB (cols 40..47 explicit 0)
        int o = wave * 16 + l16;
        f32x4 acc = mv16(slabA, wo1, o, l16, quad);
        float bv = (o < CD) ? bo1[o] : 0.f;
#pragma unroll
        for (int r = 0; r < 4; ++r) {
            float v = (o < CD) ? fmaxf(acc[r] + bv, 0.f) : 0.f;
            slabB[(quad * 4 + r) * SLB + o] = f2b(v);
        }
    }
    __syncthreads();
    if (wave < 3) {   // @W2_o2 + b -> global fp32 [n][40]
        int o = wave * 16 + l16;
        f32x4 acc = mv16(slabB, wo2, o, l16, quad);
        if (o < CD) {
            float bv = bo2[o];
#pragma unroll
            for (int r = 0; r < 4; ++r) {
                int node = node0 + quad * 4 + r;
                if (node < n) out[(size_t)node * CD + o] = acc[r] + bv;
            }
        }
    }
}

extern "C" void kernel_launch(void* const* d_in, const int* in_sizes, int n_in,
                              void* d_out, int out_size, void* d_ws, size_t ws_size,
                              hipStream_t stream)
{
    const float* x      = (const float*)d_in[0];
    const int*   ei     = (const int*)d_in[1];
    const float* w1_lin = (const float*)d_in[2];
    const float* b1_lin = (const float*)d_in[3];
    const float* w1_o1  = (const float*)d_in[4];
    const float* b1_o1  = (const float*)d_in[5];
    const float* w1_o2  = (const float*)d_in[6];
    const float* b1_o2  = (const float*)d_in[7];
    const float* w2_lin = (const float*)d_in[8];
    const float* b2_lin = (const float*)d_in[9];
    const float* w2_o1  = (const float*)d_in[10];
    const float* b2_o1  = (const float*)d_in[11];
    const float* w2_o2  = (const float*)d_in[12];
    const float* b2_o2  = (const float*)d_in[13];

    const int n = in_sizes[0] / FIN;   // 100000
    const int e = in_sizes[1] / 2;     // 1000000
    const int* src = ei;
    const int* dst = ei + e;

    // ---- d_ws layout (== R8's proven footprint) ----
    unsigned short* ws0 = (unsigned short*)d_ws;          // h1 [n][64]  12.8 MB
    unsigned short* ws2 = ws0 + (size_t)n * HD;           // h2 [n][64]  12.8 MB
    unsigned short* wb  = ws2 + (size_t)n * S2;
    unsigned short* wb1_lin = wb;                 // [64][128]
    unsigned short* wb1_o1  = wb1_lin + 64 * 128; // [64][64]
    unsigned short* wb1_o2  = wb1_o1  + 64 * 64;  // [64][64]
    unsigned short* wb2_lin = wb1_o2  + 64 * 64;  // [48][64]
    unsigned short* wb2_o1  = wb2_lin + 48 * 64;  // [48][64]
    unsigned short* wb2_o2  = wb2_o1  + 48 * 64;  // [48][64]
    uint2* pairs        = (uint2*)(wb2_o2 + 48 * 64);     // 8 MB; dead after bbuild
    int*   bucketCount  = (int*)(pairs + e);
    int*   bucketOff    = bucketCount + NBMAX;            // nb+1 entries
    int*   bucketCursor = bucketOff + NBMAX + 1;
    float* outp = (float*)d_out;

    // CSR arrays in d_out (R1-proven): built by bbuild, read by gchainB;
    // shadow-copied into the pairs region for gchainC.
    int* eidx   = (int*)d_out;
    int* deg    = eidx + e;
    int* rowptr = deg + n;
    int* ceidx   = (int*)pairs;       // CSR shadow (e+2n ints, contiguous)
    int* cdeg    = ceidx + e;
    int* crowptr = cdeg + n;

    const int nb    = (n + 255) >> 8;             // 391 buckets
    const int agrid = (e + ACH - 1) / ACH;        // 245 blocks
    const int tgrid = (n + 63) / 64;              // 1563 blocks
    const int ggrid = (n + 15) / 16;              // 6250 blocks
    const int cgrid = 150;                        // CSR-copy rider blocks
    const int c4    = (e + 2 * n) / 4;            // int4 count (e,n mult of 4)
    const int wgrid = (25600 + 255) / 256;        // 100 weight-conv blocks
    const int mv1a  = 782;                        // mv1 slabs riding with bpart
    const int mv1b  = tgrid - mv1a;               // 781 slabs riding with bbuild

    // 0. zero bucketCount
    hipMemsetAsync(bucketCount, 0, NBMAX * sizeof(int), stream);

    // 1. weight conversion + bhist rider (both independent of each other)
    prep_bhist_kernel<<<wgrid + agrid, 256, 0, stream>>>(
        w1_lin, w1_o1, w1_o2, w2_lin, w2_o1, w2_o2, wb, wgrid, dst, bucketCount, e, nb);

    // 2. bucket scan
    bscan_kernel<<<1, 256, 0, stream>>>(bucketCount, bucketOff, bucketCursor, nb);

    // 3. bpart + mv1 rider (first 782 slabs) — mv1 overlaps the CSR chain
    bpart_mv1_kernel<<<agrid + mv1a, 256, 0, stream>>>(
        src, dst, bucketCursor, pairs, e, nb, agrid, x, wb1_lin, b1_lin, ws0, n);

    // 4. bbuild + mv1 rider (remaining 781 slabs)
    bbuild_mv1_kernel<<<nb + mv1b, 256, 0, stream>>>(
        pairs, bucketOff, rowptr, deg, eidx, n, nb, mv1a, x, wb1_lin, b1_lin, ws0);

    // 5. gather1 + chainB fused -> ws2 [n][64]; rider copies CSR -> ws shadow
    gchainB_kernel<<<ggrid + cgrid, 256, 0, stream>>>(
        rowptr, deg, eidx, ws0, wb1_o1, b1_o1, wb1_o2, b1_o2, wb2_lin, b2_lin,
        ws2, n, ggrid, (const int4*)eidx, (int4*)ceidx, c4);

    // 6. gather2 + chainC fused -> out fp32 [n][40] (reads CSR shadow in ws)
    gchainC_kernel<<<ggrid, 256, 0, stream>>>(
        crowptr, cdeg, ceidx, ws2, wb2_o1, b2_o1, wb2_o2, b2_o2, outp, n);
}